// Round 8
// baseline (205.655 us; speedup 1.0000x reference)
//
#include <hip/hip_runtime.h>

typedef __attribute__((ext_vector_type(8))) short bfrag;   // 8 bf16 = 4 VGPR
typedef __attribute__((ext_vector_type(4))) float ffrag;   // MFMA 16x16 acc

#define NPAIR 24
#define PR 544            // padded rows per channel (532 used + 12 slack)
#define PC 544            // padded cols (532 used + 12 slack)
#define XPLANE (PR * PC)  // bf16 elements per channel plane

__device__ __forceinline__ unsigned short f2b(float f) {   // f32 -> bf16 RTNE
    unsigned u = __builtin_bit_cast(unsigned, f);
    return (unsigned short)((u + 0x7FFFu + ((u >> 16) & 1u)) >> 16);
}
__device__ __forceinline__ unsigned pk2(float a, float b) {
    return (unsigned)f2b(a) | ((unsigned)f2b(b) << 16);
}

// ---------- prep 1: x -> zero-padded bf16 [24][544][544] (halo baked in) ----
__global__ __launch_bounds__(256) void prep_pad(
    const float* __restrict__ x, unsigned short* __restrict__ px)
{
    int t = blockIdx.x * 256 + threadIdx.x;    // 24*544*68 = 887808 threads
    const int pc8 = t % (PC / 8);  t /= (PC / 8);
    const int pr  = t % PR;        t /= PR;
    const int bc  = t;                          // (b*3+c) 0..23
    const int sr  = pr - 10;
    const float* xp = x + (size_t)bc * (512 * 512);
    unsigned o[4];
    #pragma unroll
    for (int h = 0; h < 4; ++h) {
        const int c0 = pc8 * 8 + 2 * h - 10;
        float v0 = 0.f, v1 = 0.f;
        if ((unsigned)sr < 512u) {
            if ((unsigned)c0 < 512u)       v0 = xp[sr * 512 + c0];
            if ((unsigned)(c0 + 1) < 512u) v1 = xp[sr * 512 + c0 + 1];
        }
        o[h] = pk2(v0, v1);
    }
    *(uint4*)&px[(size_t)bc * XPLANE + pr * PC + pc8 * 8] =
        make_uint4(o[0], o[1], o[2], o[3]);
}

// ---------- prep 2: band-fragment table tabG[k][g][di][lane][8] -------------
// entry value j: a_{g,k}[16(di-1) + 8*(l>>4) - (l&15) + j], zero outside [0,21)
__global__ __launch_bounds__(256) void prep_tab(
    const float* __restrict__ bw, unsigned short* __restrict__ tabG)
{
    const int kk = blockIdx.x >> 2;          // 0..21
    const int g  = blockIdx.x & 3;
    const int di = threadIdx.x >> 6;
    const int l  = threadIdx.x & 63;
    const float* Wk = bw + (size_t)(g * 22 + kk) * 441;
    const float sq = sqrtf(Wk[220]);
    const int base = 16 * (di - 1) + 8 * (l >> 4) - (l & 15);
    unsigned o[4];
    #pragma unroll
    for (int h = 0; h < 4; ++h) {
        const int u0 = base + 2 * h, u1 = u0 + 1;
        float v0 = 0.f, v1 = 0.f;
        if ((unsigned)u0 < 21u) v0 = Wk[210 + u0] / sq;
        if ((unsigned)u1 < 21u) v1 = Wk[210 + u1] / sq;
        o[h] = pk2(v0, v1);
    }
    *(uint4*)&tabG[((size_t)blockIdx.x * 256 + threadIdx.x) * 8] =
        make_uint4(o[0], o[1], o[2], o[3]);
}

// ---------- main: two banded-MFMA passes (R6 compute, verbatim) -------------
// P2: t_g[r][c] = w_g * sum_j a_g[j] x[r][c+j]   (A = x rows, B = banded taps)
// P3: out[y][c] = sum_g sum_i a_g[i] t_g[i+y][c] (A = banded taps, B = t cols)
// R8 change (single variable): epilogue stages the 64x64 f32 tile in LDS and
// re-reads with lane->(row=tid>>4, col4=(tid&15)*4) so each wave store instr
// covers 4 full 256B rows -> 11 dwordx4/thread instead of 44 scalar dwords.
__global__ __launch_bounds__(256, 5) void gcm_main(
    const unsigned short* __restrict__ px,
    const unsigned short* __restrict__ tabG,
    const float* __restrict__ wgt,
    float* __restrict__ out)
{
    __shared__ __align__(16) short st[64 * 104];   // t transposed [col][row], 13.3KB
    __shared__ __align__(16) float sF[64 * 68];    // f32 out tile, 17.4KB

    const int tid  = threadIdx.x;
    const int lane = tid & 63;
    const int wv   = tid >> 6;
    const int ln   = lane & 15;
    const int lq   = lane >> 4;

    // XCD-aware bijective swizzle (12288 = 8 * 1536)
    const int phys = blockIdx.x;
    const int logical = (phys & 7) * 1536 + (phys >> 3);
    const int bz  = logical >> 6;
    const int rem = logical & 63;
    const int by = rem >> 3, bx = rem & 7;
    const int b = bz / NPAIR;
    const int p = bz - b * NPAIR;
    const int c = p >> 3;
    const int k = p - c;

    // ---- x fragments direct from padded bf16 global (no bounds checks)
    const int s0 = wv >> 1;
    const unsigned short* xb = px + (size_t)(b * 3 + c) * XPLANE
                             + (by * 64 + ln) * PC + bx * 64 + 32 * s0 + 8 * lq;
    bfrag xa[6][2];
    #pragma unroll
    for (int rg = 0; rg < 6; ++rg) {
        xa[rg][0] = *(const bfrag*)(xb + 16 * rg * PC);
        xa[rg][1] = *(const bfrag*)(xb + 16 * rg * PC + 32);
    }

    const unsigned short* tk = tabG + (size_t)k * (16 * 64 * 8);
    const float* wrow = wgt + (b * 4) * 22 + k;

    ffrag acc3[4];
    #pragma unroll
    for (int yg = 0; yg < 4; ++yg) acc3[yg] = ffrag{0.f, 0.f, 0.f, 0.f};

    #pragma unroll 1
    for (int g = 0; g < 4; ++g) {
        const float wg = wrow[g * 22];
        // P2: horizontal conv -> t (transposed store), scaled by wg
        const bfrag tb0 = *(const bfrag*)&tk[((g * 4 + (2 * s0 - wv + 1)) * 64 + lane) * 8];
        const bfrag tb1 = *(const bfrag*)&tk[((g * 4 + (2 * s0 + 2 - wv + 1)) * 64 + lane) * 8];
        #pragma unroll
        for (int rg = 0; rg < 6; ++rg) {
            ffrag a = ffrag{0.f, 0.f, 0.f, 0.f};
            a = __builtin_amdgcn_mfma_f32_16x16x32_bf16(xa[rg][0], tb0, a, 0, 0, 0);
            a = __builtin_amdgcn_mfma_f32_16x16x32_bf16(xa[rg][1], tb1, a, 0, 0, 0);
            // lane holds rows r=16rg+4lq+{0..3}, col c=16wv+ln
            *(uint2*)&st[(16 * wv + ln) * 104 + 16 * rg + 4 * lq] =
                make_uint2(pk2(a.x * wg, a.y * wg), pk2(a.z * wg, a.w * wg));
        }
        __syncthreads();
        // P3: vertical conv (A = banded taps, B = t cols)
        bfrag tbv[3];
        #pragma unroll
        for (int s = 0; s < 3; ++s)
            tbv[s] = *(const bfrag*)&st[(16 * wv + ln) * 104 + 32 * s + 8 * lq];
        #pragma unroll
        for (int yg = 0; yg < 4; ++yg) {
            const int sa = yg >> 1;
            #pragma unroll
            for (int si = 0; si < 2; ++si) {
                const int s  = sa + si;
                const int di = 2 * s - yg + 1;
                const bfrag ta = *(const bfrag*)&tk[((g * 4 + di) * 64 + lane) * 8];
                acc3[yg] = __builtin_amdgcn_mfma_f32_16x16x32_bf16(ta, tbv[s], acc3[yg], 0, 0, 0);
            }
        }
        if (g < 3) __syncthreads();  // before next g overwrites st
    }

    // ---- epilogue: LDS transpose to row-dense layout, then wide stores
    // acc3[yg] holds rows 16yg+4lq+{0..3}, col 16wv+ln
    #pragma unroll
    for (int yg = 0; yg < 4; ++yg) {
        const int col = 16 * wv + ln;
        sF[(16 * yg + 4 * lq + 0) * 68 + col] = acc3[yg].x;
        sF[(16 * yg + 4 * lq + 1) * 68 + col] = acc3[yg].y;
        sF[(16 * yg + 4 * lq + 2) * 68 + col] = acc3[yg].z;
        sF[(16 * yg + 4 * lq + 3) * 68 + col] = acc3[yg].w;
    }
    __syncthreads();

    const int oS = (3 * k > 22 * c) ? 3 * k : 22 * c;
    const int t1 = 3 * k + 2, t2 = 22 * c + 21;
    const int oE = (t1 < t2) ? t1 : t2;
    const int rr = tid >> 4;            // 0..15
    const int c4 = (tid & 15) * 4;      // 0..60
    #pragma unroll
    for (int it = 0; it < 4; ++it) {
        const int row = 16 * it + rr;
        const ffrag v = *(const ffrag*)&sF[row * 68 + c4];
        const int gy = by * 64 + row;
        const int gx = bx * 64 + c4;
        for (int o = oS; o <= oE; ++o) {
            float* ob = out + ((size_t)(b * 66 + o) * 512 + gy) * 512 + gx;
            *(float4*)ob = make_float4(v.x, v.y, v.z, v.w);
        }
    }
}

extern "C" void kernel_launch(void* const* d_in, const int* in_sizes, int n_in,
                              void* d_out, int out_size, void* d_ws, size_t ws_size,
                              hipStream_t stream) {
    const float* x   = (const float*)d_in[0];
    const float* wgt = (const float*)d_in[1];
    const float* bw  = (const float*)d_in[2];
    float* out = (float*)d_out;

    unsigned short* px   = (unsigned short*)d_ws;                    // 14,204,928 B
    unsigned short* tabG = (unsigned short*)((char*)d_ws + (size_t)24 * XPLANE * 2);

    prep_pad<<<dim3(24 * PR * (PC / 8) / 256), 256, 0, stream>>>(x, px);
    prep_tab<<<dim3(88), 256, 0, stream>>>(bw, tabG);
    gcm_main<<<dim3(8 * 8 * 8 * NPAIR), 256, 0, stream>>>(px, tabG, wgt, out);
}

// Round 9
// 134.675 us; speedup vs baseline: 1.5270x; 1.5270x over previous
//
#include <hip/hip_runtime.h>

typedef __attribute__((ext_vector_type(8))) short bfrag;   // 8 bf16 = 4 VGPR
typedef __attribute__((ext_vector_type(4))) float ffrag;   // MFMA 16x16 acc

#define NPAIR 24
#define PR 544            // padded rows per channel (532 used + 12 slack)
#define PC 544            // padded cols (532 used + 12 slack)
#define XPLANE (PR * PC)  // bf16 elements per channel plane

__device__ __forceinline__ unsigned short f2b(float f) {   // f32 -> bf16 RTNE
    unsigned u = __builtin_bit_cast(unsigned, f);
    return (unsigned short)((u + 0x7FFFu + ((u >> 16) & 1u)) >> 16);
}
__device__ __forceinline__ unsigned pk2(float a, float b) {
    return (unsigned)f2b(a) | ((unsigned)f2b(b) << 16);
}

// ---------- prep 1: x -> zero-padded bf16 [24][544][544] (halo baked in) ----
__global__ __launch_bounds__(256) void prep_pad(
    const float* __restrict__ x, unsigned short* __restrict__ px)
{
    int t = blockIdx.x * 256 + threadIdx.x;    // 24*544*68 = 887808 threads
    const int pc8 = t % (PC / 8);  t /= (PC / 8);
    const int pr  = t % PR;        t /= PR;
    const int bc  = t;                          // (b*3+c) 0..23
    const int sr  = pr - 10;
    const float* xp = x + (size_t)bc * (512 * 512);
    unsigned o[4];
    #pragma unroll
    for (int h = 0; h < 4; ++h) {
        const int c0 = pc8 * 8 + 2 * h - 10;
        float v0 = 0.f, v1 = 0.f;
        if ((unsigned)sr < 512u) {
            if ((unsigned)c0 < 512u)       v0 = xp[sr * 512 + c0];
            if ((unsigned)(c0 + 1) < 512u) v1 = xp[sr * 512 + c0 + 1];
        }
        o[h] = pk2(v0, v1);
    }
    *(uint4*)&px[(size_t)bc * XPLANE + pr * PC + pc8 * 8] =
        make_uint4(o[0], o[1], o[2], o[3]);
}

// ---------- prep 2: band-fragment table tabG[k][g][di][lane][8] -------------
// entry value j: a_{g,k}[16(di-1) + 8*(l>>4) - (l&15) + j], zero outside [0,21)
__global__ __launch_bounds__(256) void prep_tab(
    const float* __restrict__ bw, unsigned short* __restrict__ tabG)
{
    const int kk = blockIdx.x >> 2;          // 0..21
    const int g  = blockIdx.x & 3;
    const int di = threadIdx.x >> 6;
    const int l  = threadIdx.x & 63;
    const float* Wk = bw + (size_t)(g * 22 + kk) * 441;
    const float sq = sqrtf(Wk[220]);
    const int base = 16 * (di - 1) + 8 * (l >> 4) - (l & 15);
    unsigned o[4];
    #pragma unroll
    for (int h = 0; h < 4; ++h) {
        const int u0 = base + 2 * h, u1 = u0 + 1;
        float v0 = 0.f, v1 = 0.f;
        if ((unsigned)u0 < 21u) v0 = Wk[210 + u0] / sq;
        if ((unsigned)u1 < 21u) v1 = Wk[210 + u1] / sq;
        o[h] = pk2(v0, v1);
    }
    *(uint4*)&tabG[((size_t)blockIdx.x * 256 + threadIdx.x) * 8] =
        make_uint4(o[0], o[1], o[2], o[3]);
}

// ---------- main: R6 structure verbatim, except tab staged in LDS -----------
// P2: t_g[r][c] = w_g * sum_j a_g[j] x[r][c+j]   (A = x rows, B = banded taps)
// P3: out[y][c] = sum_g sum_i a_g[i] t_g[i+y][c] (A = banded taps, B = t cols)
// R9 single-variable change vs R6 (158.7us): the 16KB per-k band-fragment
// table is copied global->LDS once per block (coalesced uint4), removing
// ~2GB of aggregate L1/L2 read traffic from the 40 tab reads per thread.
__global__ __launch_bounds__(256, 5) void gcm_main(
    const unsigned short* __restrict__ px,
    const unsigned short* __restrict__ tabG,
    const float* __restrict__ wgt,
    float* __restrict__ out)
{
    __shared__ __align__(16) short st[64 * 104];   // t transposed, 13.3 KB
    __shared__ __align__(16) short stab[8192];     // tab slice for this k, 16 KB

    const int tid  = threadIdx.x;
    const int lane = tid & 63;
    const int wv   = tid >> 6;
    const int ln   = lane & 15;
    const int lq   = lane >> 4;

    // XCD-aware bijective swizzle (12288 = 8 * 1536)
    const int phys = blockIdx.x;
    const int logical = (phys & 7) * 1536 + (phys >> 3);
    const int bz  = logical >> 6;
    const int rem = logical & 63;
    const int by = rem >> 3, bx = rem & 7;
    const int b = bz / NPAIR;
    const int p = bz - b * NPAIR;
    const int c = p >> 3;
    const int k = p - c;

    // ---- stage tab slice: 16 KB = 1024 uint4, 4 per thread, coalesced
    {
        const uint4* src = (const uint4*)(tabG + (size_t)k * (16 * 64 * 8));
        uint4* dst = (uint4*)stab;
        #pragma unroll
        for (int i = 0; i < 4; ++i)
            dst[tid + 256 * i] = src[tid + 256 * i];
    }

    // ---- x fragments direct from padded bf16 global (no bounds checks)
    const int s0 = wv >> 1;
    const unsigned short* xb = px + (size_t)(b * 3 + c) * XPLANE
                             + (by * 64 + ln) * PC + bx * 64 + 32 * s0 + 8 * lq;
    bfrag xa[6][2];
    #pragma unroll
    for (int rg = 0; rg < 6; ++rg) {
        xa[rg][0] = *(const bfrag*)(xb + 16 * rg * PC);
        xa[rg][1] = *(const bfrag*)(xb + 16 * rg * PC + 32);
    }

    const float* wrow = wgt + (b * 4) * 22 + k;
    __syncthreads();   // stab ready

    ffrag acc3[4];
    #pragma unroll
    for (int yg = 0; yg < 4; ++yg) acc3[yg] = ffrag{0.f, 0.f, 0.f, 0.f};

    #pragma unroll 1
    for (int g = 0; g < 4; ++g) {
        const float wg = wrow[g * 22];
        // P2: horizontal conv -> t (transposed store), scaled by wg
        const bfrag tb0 = *(const bfrag*)&stab[((g * 4 + (2 * s0 - wv + 1)) * 64 + lane) * 8];
        const bfrag tb1 = *(const bfrag*)&stab[((g * 4 + (2 * s0 + 2 - wv + 1)) * 64 + lane) * 8];
        #pragma unroll
        for (int rg = 0; rg < 6; ++rg) {
            ffrag a = ffrag{0.f, 0.f, 0.f, 0.f};
            a = __builtin_amdgcn_mfma_f32_16x16x32_bf16(xa[rg][0], tb0, a, 0, 0, 0);
            a = __builtin_amdgcn_mfma_f32_16x16x32_bf16(xa[rg][1], tb1, a, 0, 0, 0);
            // lane holds rows r=16rg+4lq+{0..3}, col c=16wv+ln
            *(uint2*)&st[(16 * wv + ln) * 104 + 16 * rg + 4 * lq] =
                make_uint2(pk2(a.x * wg, a.y * wg), pk2(a.z * wg, a.w * wg));
        }
        __syncthreads();
        // P3: vertical conv (A = banded taps, B = t cols)
        bfrag tbv[3];
        #pragma unroll
        for (int s = 0; s < 3; ++s)
            tbv[s] = *(const bfrag*)&st[(16 * wv + ln) * 104 + 32 * s + 8 * lq];
        #pragma unroll
        for (int yg = 0; yg < 4; ++yg) {
            const int sa = yg >> 1;
            #pragma unroll
            for (int si = 0; si < 2; ++si) {
                const int s  = sa + si;
                const int di = 2 * s - yg + 1;
                const bfrag ta = *(const bfrag*)&stab[((g * 4 + di) * 64 + lane) * 8];
                acc3[yg] = __builtin_amdgcn_mfma_f32_16x16x32_bf16(ta, tbv[s], acc3[yg], 0, 0, 0);
            }
        }
        if (g < 3) __syncthreads();  // before next g overwrites st
    }

    // ---- fan-out stores (R6's proven scalar path)
    const int oS = (3 * k > 22 * c) ? 3 * k : 22 * c;
    const int t1 = 3 * k + 2, t2 = 22 * c + 21;
    const int oE = (t1 < t2) ? t1 : t2;
    const int gxo = bx * 64 + 16 * wv + ln;
    #pragma unroll
    for (int yg = 0; yg < 4; ++yg) {
        const int gy = by * 64 + 16 * yg + 4 * lq;
        for (int o = oS; o <= oE; ++o) {
            float* ob = out + ((size_t)(b * 66 + o) * 512 + gy) * 512 + gxo;
            ob[0]    = acc3[yg].x;
            ob[512]  = acc3[yg].y;
            ob[1024] = acc3[yg].z;
            ob[1536] = acc3[yg].w;
        }
    }
}

extern "C" void kernel_launch(void* const* d_in, const int* in_sizes, int n_in,
                              void* d_out, int out_size, void* d_ws, size_t ws_size,
                              hipStream_t stream) {
    const float* x   = (const float*)d_in[0];
    const float* wgt = (const float*)d_in[1];
    const float* bw  = (const float*)d_in[2];
    float* out = (float*)d_out;

    unsigned short* px   = (unsigned short*)d_ws;                    // 14,204,928 B
    unsigned short* tabG = (unsigned short*)((char*)d_ws + (size_t)24 * XPLANE * 2);

    prep_pad<<<dim3(24 * PR * (PC / 8) / 256), 256, 0, stream>>>(x, px);
    prep_tab<<<dim3(88), 256, 0, stream>>>(bw, tabG);
    gcm_main<<<dim3(8 * 8 * 8 * NPAIR), 256, 0, stream>>>(px, tabG, wgt, out);
}